// Round 12
// baseline (83.160 us; speedup 1.0000x reference)
//
#include <hip/hip_runtime.h>

// InstanceSegmentationLoss — 2-dispatch form (R9 verbatim revert).
//
// Reference == 33x33 joint histogram J[p][t] over 4.19M pixels + O(33^2) IoU.
//
// Session ledger:
//  - PASSED: R3 (3-dispatch u32), R4/R5 (fused + per-thread fence, fence cost
//    ~65 us), R8 (fused + 1-wave fence, 88.3), R9 (this form, 83.0).
//  - CONTAINER-KILLED: R6/R7 (fence-free single-dispatch), R10/R11 (packed
//    u64 global atomics, even natively-typed/8-aligned). Those paths are
//    closed on this stack.
//
// This form: dispatch boundary orders hist -> finalize; all cross-dispatch
// data moves via agent-scope u32 atomics at the LLC (per-XCD L2s are not
// coherent). No fences anywhere. g_part is .bss (zero at load); finalize
// re-zeroes it each call -> zero-at-entry invariant holds on every graph
// replay. Identical work every call; d_ws unused.
//
// dur_us ~83: ~55-58 us harness fixed cost (268MB ws re-poison fills at
// ~75% HBM peak) + ~5.5 us structural 33.5MB read + ~20 us flush/finalize/
// launch machinery. Effective ceiling for this harness.

#define NIDS    33               // ids 0..32 (0 = background)
#define HSIZE   (NIDS * NIDS)    // 1089
#define RSTRIDE 1152             // 1089 padded to 64B-line multiple (u32 units)
#define NREP    32               // histogram replicas (spread LLC line traffic)

__device__ unsigned g_part[NREP * RSTRIDE];  // zero-init, self-cleaned

__device__ __forceinline__ int clamp_id(float v) {
    int i = (int)v;
    i = i < 0 ? 0 : i;
    return i > (NIDS - 1) ? (NIDS - 1) : i;
}

__device__ __forceinline__ void bin4(unsigned* sh, float4 p, float4 t) {
    atomicAdd(&sh[clamp_id(p.x) * NIDS + clamp_id(t.x)], 1u);
    atomicAdd(&sh[clamp_id(p.y) * NIDS + clamp_id(t.y)], 1u);
    atomicAdd(&sh[clamp_id(p.z) * NIDS + clamp_id(t.z)], 1u);
    atomicAdd(&sh[clamp_id(p.w) * NIDS + clamp_id(t.w)], 1u);
}

__global__ void __launch_bounds__(1024)
hist_kernel(const float4* __restrict__ pred,
            const float4* __restrict__ tmask, int n4) {
    __shared__ unsigned sh[HSIZE];

    const int tid = threadIdx.x;
    for (int i = tid; i < HSIZE; i += blockDim.x) sh[i] = 0u;
    __syncthreads();

    // per-block LDS histogram, 4-way unrolled float4 loads
    const int tot = gridDim.x * blockDim.x;   // 262144 -> exactly 4 float4/thread
    int i = blockIdx.x * blockDim.x + tid;
    for (; i + 3 * tot < n4; i += 4 * tot) {
        float4 p0 = pred[i],           t0 = tmask[i];
        float4 p1 = pred[i + tot],     t1 = tmask[i + tot];
        float4 p2 = pred[i + 2 * tot], t2 = tmask[i + 2 * tot];
        float4 p3 = pred[i + 3 * tot], t3 = tmask[i + 3 * tot];
        bin4(sh, p0, t0);
        bin4(sh, p1, t1);
        bin4(sh, p2, t2);
        bin4(sh, p3, t3);
    }
    for (; i < n4; i += tot) bin4(sh, pred[i], tmask[i]);
    __syncthreads();

    // flush to replica (blockIdx & 31): agent-scope atomics at the LLC.
    // No fence — the dispatch boundary orders this vs finalize_kernel.
    unsigned* rep = &g_part[(blockIdx.x & (NREP - 1)) * RSTRIDE];
    for (int j = tid; j < HSIZE; j += blockDim.x) {
        unsigned v = sh[j];
        if (v) atomicAdd(&rep[j], v);
    }
}

__global__ void __launch_bounds__(1024)
finalize_kernel(float* __restrict__ out) {
    __shared__ float shf[HSIZE];
    __shared__ float rowsum[NIDS], colsum[NIDS];
    __shared__ float maxv[32];

    const int tid = threadIdx.x;
    // reduce 32 replicas (agent-scope loads at LLC — always coherent)
    for (int j = tid; j < HSIZE; j += blockDim.x) {
        unsigned s = 0u;
        #pragma unroll
        for (int r = 0; r < NREP; ++r)
            s += __hip_atomic_load(&g_part[r * RSTRIDE + j], __ATOMIC_RELAXED,
                                   __HIP_MEMORY_SCOPE_AGENT);
        shf[j] = (float)s;
    }
    // re-zero for next call (agent-scope stores -> land at LLC, next call's
    // flush atomics see them)
    for (int j = tid; j < NREP * RSTRIDE; j += blockDim.x)
        __hip_atomic_store(&g_part[j], 0u, __ATOMIC_RELAXED,
                           __HIP_MEMORY_SCOPE_AGENT);
    __syncthreads();

    if (tid < NIDS) {
        float rs = 0.f, cs = 0.f;
        for (int j = 0; j < NIDS; ++j) {
            rs += shf[tid * NIDS + j];
            cs += shf[j * NIDS + tid];
        }
        rowsum[tid] = rs;
        colsum[tid] = cs;
    }
    __syncthreads();

    if (tid < 32) {
        const int n = tid + 1;  // pred instance 1..32
        float best = 0.f;
        const float rs = rowsum[n];
        for (int m = 1; m < NIDS; ++m) {
            float inter = shf[n * NIDS + m];
            float uni   = rs + colsum[m] - inter;
            float iou   = (uni > 0.f) ? (inter / uni) : 0.f;
            best = fmaxf(best, iou);
        }
        maxv[tid] = best;
    }
    __syncthreads();

    if (tid == 0) {
        double sp = 0.0, st = 0.0;
        for (int k = 1; k < NIDS; ++k) {
            sp += (double)k * (double)rowsum[k];
            st += (double)k * (double)colsum[k];
        }
        float loss = 0.f;
        for (int k = 0; k < 32; ++k) loss += 1.0f - maxv[k];
        out[0] = loss + (float)((sp + st) * 1e-12);
    }
}

extern "C" void kernel_launch(void* const* d_in, const int* in_sizes, int n_in,
                              void* d_out, int out_size, void* d_ws, size_t ws_size,
                              hipStream_t stream) {
    const float* pred  = (const float*)d_in[0];
    const float* tmask = (const float*)d_in[1];
    float* out = (float*)d_out;

    const int n  = in_sizes[0];  // 2048*2048 = 4194304
    const int n4 = n / 4;

    // 256 blocks x 1024 threads: 1 block/CU, 16 waves/CU; exactly 4 float4
    // pairs per thread; flush = 279K atomics spread over 32 replicas.
    hist_kernel<<<256, 1024, 0, stream>>>((const float4*)pred,
                                          (const float4*)tmask, n4);
    finalize_kernel<<<1, 1024, 0, stream>>>(out);
}